// Round 4
// baseline (852.039 us; speedup 1.0000x reference)
//
#include <hip/hip_runtime.h>
#include <cstdint>
#include <cstddef>

#define BATCH 256
#define VOCAB 128000
#define V4 (VOCAB/4)
#define NBINS 4096
#define CAP 4096            // power of 2: bitonic padding can never overflow
#define SPILLCAP 6144       // candidate-index spill (l >= 8): E~5.7K, +5 sigma margin
#define GATE_SPILL 8.0f
#define SPILL_BIN 3088u     // fkey(bits(8.0f)) >> 20
#define M44 0xFFFFFFFFFFFull
#define FIX 16777216.0f     // 2^24 fixed-point mass scale
#define FIXINV 5.9604644775390625e-8f

__device__ __forceinline__ uint32_t rotl32(uint32_t v, int r){ return (v<<r)|(v>>(32-r)); }

// threefry2x32 with key (0,1) — jax.random.key(1) -> key data [0,1]
__device__ __forceinline__ void threefry2x32_01(uint32_t& x0, uint32_t& x1){
  const uint32_t ks0=0u, ks1=1u, ks2=0x1BD11BDAu ^ 0u ^ 1u;
  x0+=ks0; x1+=ks1;
#define TF_R(r) { x0+=x1; x1=rotl32(x1,(r)); x1^=x0; }
  TF_R(13) TF_R(15) TF_R(26) TF_R(6)
  x0+=ks1; x1+=ks2+1u;
  TF_R(17) TF_R(29) TF_R(16) TF_R(24)
  x0+=ks2; x1+=ks0+2u;
  TF_R(13) TF_R(15) TF_R(26) TF_R(6)
  x0+=ks0; x1+=ks1+3u;
  TF_R(17) TF_R(29) TF_R(16) TF_R(24)
  x0+=ks1; x1+=ks2+4u;
  TF_R(13) TF_R(15) TF_R(26) TF_R(6)
  x0+=ks2; x1+=ks0+5u;
#undef TF_R
}

// JAX partitionable threefry draw: counter=(0,z), bits = x0 ^ x1. Verified (absmax 0).
__device__ __forceinline__ float gumbel_at(uint32_t z){
  uint32_t x0 = 0u, x1 = z;
  threefry2x32_01(x0, x1);
  uint32_t bits = x0 ^ x1;
  uint32_t fb = (bits >> 9) | 0x3F800000u;
  float f = __uint_as_float(fb) - 1.0f;
  const float tiny = 1.17549435e-38f;
  float uu = fmaxf(tiny, f + tiny);
  return -logf(-logf(uu));
}

__device__ __forceinline__ uint32_t fkey(uint32_t u){
  return (u >> 31) ? ~u : (u | 0x80000000u);
}
__device__ __forceinline__ float pdecode(unsigned long long k){
  return __uint_as_float(~(uint32_t)(k >> 32));
}

// ---------- kernel 0: zero per-row spill counters ----------
__global__ void k_zero(unsigned* __restrict__ cnt){
  if (threadIdx.x < BATCH) cnt[threadIdx.x] = 0u;
}

// ---------- kernel 1: pure streaming (4 blocks per row, 256 threads) ----------
// Per block (row b, quarter q): fill out quarter, local max, sum e^(l-16),
// ballot-compacted spill of indices with l >= 8 into global ws.
// NO LDS atomics, NO histogram -> compiler can pipeline; 4 blocks/CU hide latency.
__global__ __launch_bounds__(256) void k_stream(
    const float* __restrict__ scores, const float* __restrict__ green,
    float* __restrict__ out, unsigned* __restrict__ cnt,
    float* __restrict__ pmax, float* __restrict__ psum,
    unsigned* __restrict__ spill)
{
  __shared__ float red[256];

  const int blk = blockIdx.x;
  const int b = blk >> 2, q = blk & 3;
  const int tid = threadIdx.x, lane = tid & 63;
  const int base = q * 8000;                       // float4 index base (V4/4 = 8000)
  const float4* row4 = (const float4*)(scores + (size_t)b * VOCAB);
  const float4* grn4 = (const float4*)green;
  float4* o4 = (float4*)(out + (size_t)b * VOCAB);
  unsigned* sp_row = spill + (size_t)b * SPILLCAP;
  const float4 fv = make_float4(1e-5f, 1e-5f, 1e-5f, 1e-5f);

  float lm = -INFINITY, ls16 = 0.f;

#define SPILL1(LV, IDX) do { \
    float l_ = (LV); \
    lm = fmaxf(lm, l_); \
    ls16 += expf(l_ - 16.0f); \
    bool pr_ = (l_ >= GATE_SPILL); \
    unsigned long long mk_ = __ballot(pr_); \
    if (pr_){ \
      unsigned off_ = (unsigned)__popcll(mk_ & ((1ull << lane) - 1ull)); \
      unsigned base_ = 0u; \
      if (off_ == 0u) base_ = atomicAdd(&cnt[b], (unsigned)__popcll(mk_)); \
      base_ = (unsigned)__shfl((int)base_, (int)(__ffsll(mk_) - 1), 64); \
      unsigned pos_ = base_ + off_; \
      if (pos_ < SPILLCAP) sp_row[pos_] = (IDX); \
    } \
  } while(0)

#define SPROC4(SV, GV, II) do { \
    SPILL1(fmaf(2.f, (GV).x, (SV).x), (unsigned)(4*(II)+0)); \
    SPILL1(fmaf(2.f, (GV).y, (SV).y), (unsigned)(4*(II)+1)); \
    SPILL1(fmaf(2.f, (GV).z, (SV).z), (unsigned)(4*(II)+2)); \
    SPILL1(fmaf(2.f, (GV).w, (SV).w), (unsigned)(4*(II)+3)); \
  } while(0)

  // 8000 float4s per block = 7 quad-strides (7168) + 3 singles (768) + 64-partial
  for (int g7 = 0; g7 < 7; ++g7){
    const int i0 = base + tid + g7*1024, i1 = i0+256, i2 = i0+512, i3 = i0+768;
    float4 sa = row4[i0], sb = row4[i1], sc = row4[i2], sd = row4[i3];
    float4 ga = grn4[i0], gb = grn4[i1], gc = grn4[i2], gd = grn4[i3];
    o4[i0] = fv; o4[i1] = fv; o4[i2] = fv; o4[i3] = fv;
    SPROC4(sa, ga, i0); SPROC4(sb, gb, i1); SPROC4(sc, gc, i2); SPROC4(sd, gd, i3);
  }
  {
    const int i0 = base + 7168 + tid, i1 = i0+256, i2 = i0+512;
    float4 sa = row4[i0], sb = row4[i1], sc = row4[i2];
    float4 ga = grn4[i0], gb = grn4[i1], gc = grn4[i2];
    o4[i0] = fv; o4[i1] = fv; o4[i2] = fv;
    SPROC4(sa, ga, i0); SPROC4(sb, gb, i1); SPROC4(sc, gc, i2);
  }
  if (tid < 64){                                   // one whole wave: ballots uniform
    const int i0 = base + 7936 + tid;
    float4 sa = row4[i0];
    float4 ga = grn4[i0];
    o4[i0] = fv;
    SPROC4(sa, ga, i0);
  }
#undef SPROC4
#undef SPILL1

  // block reductions (fixed trees) -> per-(row,quarter) partials
  red[tid] = lm; __syncthreads();
  for (int s = 128; s > 0; s >>= 1){ if (tid < s) red[tid] = fmaxf(red[tid], red[tid+s]); __syncthreads(); }
  if (tid == 0) pmax[b*4 + q] = red[0];
  __syncthreads();
  red[tid] = ls16; __syncthreads();
  for (int s = 128; s > 0; s >>= 1){ if (tid < s) red[tid] += red[tid+s]; __syncthreads(); }
  if (tid == 0) psum[b*4 + q] = red[0];
}

// ---------- kernel 2: per-row select + sort + sample (256 blocks x 1024) ----------
__global__ __launch_bounds__(1024) void k_row(
    const float* __restrict__ scores, const float* __restrict__ green,
    float* __restrict__ out, const unsigned* __restrict__ cnt,
    const float* __restrict__ pmax, const float* __restrict__ psum,
    const unsigned* __restrict__ spill)
{
  __shared__ unsigned long long sp64[SPILLCAP];          // 48 KB: (l_bits<<32)|idx
  __shared__ union {
    unsigned long long hist[NBINS];                      // 32 KB packed count|mass
    unsigned long long skeys[CAP];                       // 32 KB sort keys
  } u;
  __shared__ float red[1024];
  __shared__ unsigned long long wavewin[16];
  __shared__ unsigned n_sh, thr_sh, fb_sh;
  __shared__ int cut_sh;

  const int b = blockIdx.x, tid = threadIdx.x;
  const float* srow = scores + (size_t)b * VOCAB;
  float* orow = out + (size_t)b * VOCAB;

  // m exact (max assoc.), S16 in fixed order (deterministic)
  const float m = fmaxf(fmaxf(pmax[b*4+0], pmax[b*4+1]), fmaxf(pmax[b*4+2], pmax[b*4+3]));
  const float S16 = ((psum[b*4+0] + psum[b*4+1]) + psum[b*4+2]) + psum[b*4+3];
  const unsigned nsp_total = cnt[b];
  const unsigned nsp = nsp_total > SPILLCAP ? SPILLCAP : nsp_total;

  for (int i = tid; i < NBINS; i += 1024) u.hist[i] = 0ull;
  if (tid == 0) n_sh = 0u;
  __syncthreads();

  // rebuild l for spilled candidates (scattered L3-resident loads), stash in LDS,
  // build packed count|mass hist over candidates only (~6 atomics/thread).
  for (unsigned j = tid; j < nsp; j += 1024){
    unsigned idx = spill[(size_t)b * SPILLCAP + j];
    float l = fmaf(2.f, green[idx], srow[idx]);
    sp64[j] = ((unsigned long long)__float_as_uint(l) << 32) | idx;
    uint32_t bin = fkey(__float_as_uint(l)) >> 20;
    atomicAdd(&u.hist[bin],
              (1ull << 44) | (unsigned long long)(expf(l - 16.0f) * FIX));
  }
  __syncthreads();

  // threshold scan vs TRUE total S16 (hist covers l>=8: 98.9% of mass >> 0.903 target)
  if (tid == 0){
    float target = 0.903f * S16;
    int top = (int)(fkey(__float_as_uint(m)) >> 20);   // bins above bin(m) empty
    float acc = 0.f; unsigned c = 0; unsigned result = (unsigned)top;
    for (int bin = top; bin >= 0; --bin){
      unsigned long long h = u.hist[bin];
      unsigned cb = (unsigned)(h >> 44);
      if (c + cb > CAP) break;
      acc += (float)(h & M44) * FIXINV; c += cb; result = (unsigned)bin;
      if (acc >= target){
        if (bin > 0 && c + (unsigned)(u.hist[bin-1] >> 44) <= CAP)
          result = (unsigned)(bin-1);                  // safety bin
        break;
      }
    }
    thr_sh = result;
    fb_sh = (nsp_total > SPILLCAP || result < SPILL_BIN) ? 1u : 0u;
  }
  __syncthreads();                    // hist reads done; skeys (union) writable
  const unsigned thr = thr_sh;

  // candidate build: from LDS stash (normal) or full-row re-read (fallback)
  if (!fb_sh){
    for (unsigned j = tid; j < nsp; j += 1024){
      unsigned long long k = sp64[j];
      uint32_t lb = (uint32_t)(k >> 32);
      if ((fkey(lb) >> 20) >= thr){
        unsigned pos = atomicAdd(&n_sh, 1u);
        float p = expf(__uint_as_float(lb) - 16.0f) / S16;
        if (pos < CAP)
          u.skeys[pos] = ((unsigned long long)(~__float_as_uint(p)) << 32) | (k & 0xFFFFFFFFull);
      }
    }
  } else {
    const float4* row4 = (const float4*)srow;
    const float4* grn4 = (const float4*)green;
    for (int i = tid; i < V4; i += 1024){
      float4 s = row4[i], g = grn4[i];
      #pragma unroll
      for (int c = 0; c < 4; ++c){
        float l = fmaf(2.f, (&g.x)[c], (&s.x)[c]);
        if ((fkey(__float_as_uint(l)) >> 20) >= thr){
          unsigned pos = atomicAdd(&n_sh, 1u);
          float p = expf(l - 16.0f) / S16;
          if (pos < CAP)
            u.skeys[pos] = ((unsigned long long)(~__float_as_uint(p)) << 32) | (unsigned)(4*i + c);
        }
      }
    }
  }
  __syncthreads();
  unsigned n = n_sh; if (n > CAP) n = CAP;   // scan guarantees <= CAP

  // pad + bitonic sort (ascending == p desc, stable via embedded idx)
  unsigned N2 = 2; while (N2 < n) N2 <<= 1;
  for (unsigned i = n + tid; i < N2; i += 1024) u.skeys[i] = 0xFFFFFFFFFFFFFFFFull;
  __syncthreads();
  for (unsigned k = 2; k <= N2; k <<= 1){
    for (unsigned j = k >> 1; j > 0; j >>= 1){
      for (unsigned i = tid; i < N2; i += 1024){
        unsigned ixj = i ^ j;
        if (ixj > i){
          unsigned long long a = u.skeys[i], c2 = u.skeys[ixj];
          bool up = ((i & k) == 0u);
          if ((a > c2) == up){ u.skeys[i] = c2; u.skeys[ixj] = a; }
        }
      }
      __syncthreads();
    }
  }

  // 0.9 cumsum crossing (chunked partials in red[], thread-0 walk)
  unsigned C = (n + 1023) >> 10;
  {
    unsigned lo = tid * C; if (lo > n) lo = n;
    unsigned hi = lo + C;  if (hi > n) hi = n;
    float s = 0.f;
    for (unsigned j = lo; j < hi; ++j) s += pdecode(u.skeys[j]);
    red[tid] = s;
  }
  __syncthreads();
  if (tid == 0){
    float run = 0.f; int cut = (int)n - 1; int t = 0;
    for (; t < 1024; ++t){ float cs = red[t]; if (run + cs >= 0.9f) break; run += cs; }
    if (t < 1024){
      float c2 = run;
      for (unsigned j = (unsigned)t * C; j < n; ++j){
        c2 += pdecode(u.skeys[j]);
        if (c2 >= 0.9f){ cut = (int)j; break; }
      }
    }
    cut_sh = cut;
  }
  __syncthreads();
  const int cut = cut_sh;

  // gumbel argmax over sorted positions 0..cut
  float best = -INFINITY; unsigned bj = 0x7FFFFFFFu;
  for (int j = tid; j <= cut; j += 1024){
    float p = pdecode(u.skeys[j]);
    float sc = logf(p) + gumbel_at((uint32_t)b * (uint32_t)VOCAB + (uint32_t)j);
    if (sc > best || (sc == best && (unsigned)j < bj)){ best = sc; bj = (unsigned)j; }
  }
  for (int off = 32; off > 0; off >>= 1){
    float osc = __shfl_down(best, off, 64);
    unsigned oj = __shfl_down(bj, off, 64);
    if (osc > best || (osc == best && oj < bj)){ best = osc; bj = oj; }
  }
  if ((tid & 63) == 0){
    uint32_t ub = __float_as_uint(best);
    uint32_t ou = (ub >> 31) ? ~ub : (ub | 0x80000000u);
    wavewin[tid >> 6] = ((unsigned long long)ou << 32) |
                        (unsigned long long)(0xFFFFFFFFu - bj);   // tie -> min j
  }
  __syncthreads();
  if (tid == 0){
    unsigned long long bb = 0ull;
    for (int w = 0; w < 16; ++w){ unsigned long long x = wavewin[w]; if (x > bb) bb = x; }
    unsigned jwin = 0xFFFFFFFFu - (unsigned)(bb & 0xFFFFFFFFull);
    // k_stream's 1e-5 fill is ordered before this dispatch (same stream).
    orow[(size_t)(u.skeys[jwin] & 0xFFFFFFFFull)] = 1e5f;
  }
}

extern "C" void kernel_launch(void* const* d_in, const int* in_sizes, int n_in,
                              void* d_out, int out_size, void* d_ws, size_t ws_size,
                              hipStream_t stream) {
  // d_in[0]=input_ids (unused), d_in[1]=scores [256*128000] f32, d_in[2]=green [128000] f32
  const float* scores = (const float*)d_in[1];
  const float* green  = (const float*)d_in[2];
  float* out = (float*)d_out;

  // ws layout: cnt[256] u32 | pmax[1024] f32 | psum[1024] f32 | spill[256*6144] u32 (~6.3 MB)
  unsigned* cnt = (unsigned*)d_ws;
  float* pmax = (float*)d_ws + 256;
  float* psum = pmax + 1024;
  unsigned* spill = (unsigned*)(psum + 1024);
  (void)ws_size;

  hipLaunchKernelGGL(k_zero,   dim3(1),       dim3(256),  0, stream, cnt);
  hipLaunchKernelGGL(k_stream, dim3(BATCH*4), dim3(256),  0, stream, scores, green, out, cnt, pmax, psum, spill);
  hipLaunchKernelGGL(k_row,    dim3(BATCH),   dim3(1024), 0, stream, scores, green, out, cnt, pmax, psum, spill);
}

// Round 5
// 342.344 us; speedup vs baseline: 2.4888x; 2.4888x over previous
//
#include <hip/hip_runtime.h>
#include <cstdint>
#include <cstddef>

#define BATCH 256
#define VOCAB 128000
#define V4 (VOCAB/4)
#define NBINS 4096
#define CAP 4096            // power of 2: bitonic padding can never overflow
#define WSEG 256            // per-wave spill capacity (u64): E~179 hits, +5.9 sigma
#define NSEG 32             // waves per row (8 blocks x 4 waves)
#define SPILLCAP 6144       // per-row compacted cap (48KB LDS): E~5734, +5.5 sigma
#define GATE_SPILL 8.0f
#define SPILL_BIN 3088u     // fkey(bits(8.0f)) >> 20 (8.0 is a bin boundary)
#define GATE_HIST 1.0f
#define M44 0xFFFFFFFFFFFull
#define FIX 16777216.0f     // 2^24 fixed-point mass scale (deterministic hist)
#define FIXINV 5.9604644775390625e-8f

__device__ __forceinline__ uint32_t rotl32(uint32_t v, int r){ return (v<<r)|(v>>(32-r)); }

// threefry2x32 with key (0,1) — jax.random.key(1) -> key data [0,1]
__device__ __forceinline__ void threefry2x32_01(uint32_t& x0, uint32_t& x1){
  const uint32_t ks0=0u, ks1=1u, ks2=0x1BD11BDAu ^ 0u ^ 1u;
  x0+=ks0; x1+=ks1;
#define TF_R(r) { x0+=x1; x1=rotl32(x1,(r)); x1^=x0; }
  TF_R(13) TF_R(15) TF_R(26) TF_R(6)
  x0+=ks1; x1+=ks2+1u;
  TF_R(17) TF_R(29) TF_R(16) TF_R(24)
  x0+=ks2; x1+=ks0+2u;
  TF_R(13) TF_R(15) TF_R(26) TF_R(6)
  x0+=ks0; x1+=ks1+3u;
  TF_R(17) TF_R(29) TF_R(16) TF_R(24)
  x0+=ks1; x1+=ks2+4u;
  TF_R(13) TF_R(15) TF_R(26) TF_R(6)
  x0+=ks2; x1+=ks0+5u;
#undef TF_R
}

// JAX partitionable threefry draw: counter=(0,z), bits = x0 ^ x1. Verified (absmax 0).
__device__ __forceinline__ float gumbel_at(uint32_t z){
  uint32_t x0 = 0u, x1 = z;
  threefry2x32_01(x0, x1);
  uint32_t bits = x0 ^ x1;
  uint32_t fb = (bits >> 9) | 0x3F800000u;
  float f = __uint_as_float(fb) - 1.0f;
  const float tiny = 1.17549435e-38f;
  float uu = fmaxf(tiny, f + tiny);
  return -logf(-logf(uu));
}

__device__ __forceinline__ uint32_t fkey(uint32_t u){
  return (u >> 31) ? ~u : (u | 0x80000000u);
}
__device__ __forceinline__ float pdecode(unsigned long long k){
  return __uint_as_float(~(uint32_t)(k >> 32));
}

// ---------- kernel 1: pure streaming, 8 blocks/row x 256 threads ----------
// Per wave: private spill segment, REGISTER counter (no atomics anywhere),
// ballot-compacted (l_bits,idx) spill of l >= 8. No LDS. Nothing in the loop
// waits on memory round-trips -> compiler can pipeline; 8 blocks/CU hide latency.
__global__ __launch_bounds__(256) void k_stream(
    const float* __restrict__ scores, const float* __restrict__ green,
    float* __restrict__ out, unsigned long long* __restrict__ spill,
    unsigned* __restrict__ counts, float* __restrict__ pmax,
    float* __restrict__ psum)
{
  const int blk = blockIdx.x;
  const int b = blk >> 3, q = blk & 7;
  const int tid = threadIdx.x, lane = tid & 63, wv = tid >> 6;
  const int base = q * 4000;                       // float4 base (V4/8 = 4000)
  const float4* row4 = (const float4*)(scores + (size_t)b * VOCAB);
  const float4* grn4 = (const float4*)green;
  float4* o4 = (float4*)(out + (size_t)b * VOCAB);
  const int sidx = (q << 2) | wv;
  unsigned long long* seg = spill + ((size_t)b * NSEG + sidx) * WSEG;
  const float4 fv = make_float4(1e-5f, 1e-5f, 1e-5f, 1e-5f);

  float lm = -INFINITY, ls16 = 0.f;
  unsigned wcnt = 0u;                              // wave-uniform, in-register

#define SP1(LV, IDX) do { \
    float l_ = (LV); \
    lm = fmaxf(lm, l_); \
    ls16 += expf(l_ - 16.0f); \
    bool pr_ = (l_ >= GATE_SPILL); \
    unsigned long long mk_ = __ballot(pr_); \
    if (pr_){ \
      unsigned pos_ = wcnt + (unsigned)__popcll(mk_ & ((1ull << lane) - 1ull)); \
      if (pos_ < WSEG) \
        seg[pos_] = ((unsigned long long)__float_as_uint(l_) << 32) | (IDX); \
    } \
    wcnt += (unsigned)__popcll(mk_); \
  } while(0)

#define SP4(SV, GV, II) do { \
    SP1(fmaf(2.f, (GV).x, (SV).x), (unsigned)(4*(II)+0)); \
    SP1(fmaf(2.f, (GV).y, (SV).y), (unsigned)(4*(II)+1)); \
    SP1(fmaf(2.f, (GV).z, (SV).z), (unsigned)(4*(II)+2)); \
    SP1(fmaf(2.f, (GV).w, (SV).w), (unsigned)(4*(II)+3)); \
  } while(0)

  // 4000 float4s per block = 3 quad-strides (3072) + 3 singles (768) + 160-tail
  for (int g = 0; g < 3; ++g){
    const int i0 = base + tid + g*1024, i1 = i0+256, i2 = i0+512, i3 = i0+768;
    float4 sa = row4[i0], sb = row4[i1], sc = row4[i2], sd = row4[i3];
    float4 ga = grn4[i0], gb = grn4[i1], gc = grn4[i2], gd = grn4[i3];
    o4[i0] = fv; o4[i1] = fv; o4[i2] = fv; o4[i3] = fv;
    SP4(sa, ga, i0); SP4(sb, gb, i1); SP4(sc, gc, i2); SP4(sd, gd, i3);
  }
  {
    const int i0 = base + 3072 + tid, i1 = i0+256, i2 = i0+512;
    float4 sa = row4[i0], sb = row4[i1], sc = row4[i2];
    float4 ga = grn4[i0], gb = grn4[i1], gc = grn4[i2];
    o4[i0] = fv; o4[i1] = fv; o4[i2] = fv;
    SP4(sa, ga, i0); SP4(sb, gb, i1); SP4(sc, gc, i2);
  }
  if (tid < 160){
    // waves 0,1 full; wave 2 half-active (ballot covers active lanes only;
    // lane 0 of wave 2 is active so its final wcnt is correct); wave 3 idle.
    const int i0 = base + 3840 + tid;
    float4 sa = row4[i0];
    float4 ga = grn4[i0];
    o4[i0] = fv;
    SP4(sa, ga, i0);
  }
#undef SP4
#undef SP1

  // per-wave reductions (fixed shfl butterfly -> deterministic), lane0 writes
  for (int off = 32; off > 0; off >>= 1){
    lm = fmaxf(lm, __shfl_down(lm, off, 64));
    ls16 += __shfl_down(ls16, off, 64);
  }
  if (lane == 0){
    const int gi = b * NSEG + sidx;
    pmax[gi] = lm; psum[gi] = ls16; counts[gi] = wcnt;
  }
}

// ---------- kernel 2: per-row select + sort + sample (256 blocks x 1024) ----------
__global__ __launch_bounds__(1024) void k_row(
    const float* __restrict__ scores, const float* __restrict__ green,
    float* __restrict__ out, const unsigned long long* __restrict__ spill,
    const unsigned* __restrict__ counts, const float* __restrict__ pmax,
    const float* __restrict__ psum)
{
  __shared__ unsigned long long sp64[SPILLCAP];          // 48 KB (l_bits<<32)|idx
  __shared__ union {
    unsigned long long hist[NBINS];                      // 32 KB packed count|mass
    unsigned long long skeys[CAP];                       // 32 KB sort keys
  } u;
  __shared__ float red[1024];
  __shared__ unsigned long long wavewin[16];
  __shared__ unsigned segoff[NSEG + 1];
  __shared__ float m_sh, s16_sh;
  __shared__ unsigned n_sh, thr_sh, fb_sh;
  __shared__ int cut_sh;

  const int b = blockIdx.x, tid = threadIdx.x;
  const float* srow = scores + (size_t)b * VOCAB;
  float* orow = out + (size_t)b * VOCAB;

  for (int i = tid; i < NBINS; i += 1024) u.hist[i] = 0ull;
  if (tid == 0){
    unsigned tot = 0u, fb = 0u;
    float mm = -INFINITY, ss = 0.f;
    for (int s = 0; s < NSEG; ++s){
      unsigned c = counts[b*NSEG + s];
      segoff[s] = tot;
      if (c > WSEG) fb = 1u;                 // wave segment overflowed (never expected)
      tot += c;
      mm = fmaxf(mm, pmax[b*NSEG + s]);      // max: order-free, exact
      ss += psum[b*NSEG + s];                // fixed order: deterministic
    }
    segoff[NSEG] = tot;
    if (tot > SPILLCAP) fb = 1u;
    m_sh = mm; s16_sh = ss; fb_sh = fb; n_sh = 0u;
  }
  __syncthreads();
  const float m = m_sh, S16 = s16_sh;
  const unsigned tot = segoff[NSEG];
  unsigned fb = fb_sh;

  if (!fb){
    // coalesced gather of 32 segments into compacted sp64
    for (int s = 0; s < NSEG; ++s){
      const unsigned c0 = segoff[s], cl = segoff[s+1] - c0;
      const unsigned long long* seg = spill + ((size_t)b*NSEG + s)*WSEG;
      for (unsigned j = tid; j < cl; j += 1024) sp64[c0 + j] = seg[j];
    }
    __syncthreads();
    // candidate-only hist (~6 atomics/thread)
    for (unsigned j = tid; j < tot; j += 1024){
      uint32_t lb = (uint32_t)(sp64[j] >> 32);
      atomicAdd(&u.hist[fkey(lb) >> 20],
                (1ull<<44) | (unsigned long long)(expf(__uint_as_float(lb) - 16.0f) * FIX));
    }
    __syncthreads();
    // threshold scan vs TRUE total S16 (hist covers l>=8: ~99% of mass >> 0.903)
    if (tid == 0){
      float target = 0.903f * S16;
      int top = (int)(fkey(__float_as_uint(m)) >> 20);   // bins above bin(m) empty
      float acc = 0.f; unsigned c = 0; unsigned result = (unsigned)top;
      for (int bin = top; bin >= 0; --bin){
        unsigned long long h = u.hist[bin];
        unsigned cb = (unsigned)(h >> 44);
        if (c + cb > CAP) break;
        acc += (float)(h & M44) * FIXINV; c += cb; result = (unsigned)bin;
        if (acc >= target){
          if (bin > 0 && c + (unsigned)(u.hist[bin-1] >> 44) <= CAP)
            result = (unsigned)(bin-1);                  // safety bin
          break;
        }
      }
      thr_sh = result;
      if (result < SPILL_BIN) fb_sh = 1u;   // spill-hist incomplete below l=8
    }
    __syncthreads();
    fb = fb_sh;
  }

  if (fb){
    // full-row fallback (never taken on this input): complete hist, rescan, extract
    for (int i = tid; i < NBINS; i += 1024) u.hist[i] = 0ull;
    __syncthreads();
    const float4* row4 = (const float4*)srow;
    const float4* grn4 = (const float4*)green;
    for (int i = tid; i < V4; i += 1024){
      float4 s = row4[i], g = grn4[i];
      #pragma unroll
      for (int c = 0; c < 4; ++c){
        float l = fmaf(2.f, (&g.x)[c], (&s.x)[c]);
        if (l >= GATE_HIST)
          atomicAdd(&u.hist[fkey(__float_as_uint(l)) >> 20],
                    (1ull<<44) | (unsigned long long)(expf(l - 16.0f) * FIX));
      }
    }
    __syncthreads();
    if (tid == 0){
      float target = 0.903f * S16;
      int top = (int)(fkey(__float_as_uint(m)) >> 20);
      float acc = 0.f; unsigned c = 0; unsigned result = (unsigned)top;
      for (int bin = top; bin >= 0; --bin){
        unsigned long long h = u.hist[bin];
        unsigned cb = (unsigned)(h >> 44);
        if (c + cb > CAP) break;
        acc += (float)(h & M44) * FIXINV; c += cb; result = (unsigned)bin;
        if (acc >= target){
          if (bin > 0 && c + (unsigned)(u.hist[bin-1] >> 44) <= CAP)
            result = (unsigned)(bin-1);
          break;
        }
      }
      thr_sh = result;
    }
    __syncthreads();
    const unsigned thr = thr_sh;
    for (int i = tid; i < V4; i += 1024){
      float4 s = row4[i], g = grn4[i];
      #pragma unroll
      for (int c = 0; c < 4; ++c){
        float l = fmaf(2.f, (&g.x)[c], (&s.x)[c]);
        if ((fkey(__float_as_uint(l)) >> 20) >= thr){
          unsigned pos = atomicAdd(&n_sh, 1u);
          float p = expf(l - 16.0f) / S16;
          if (pos < CAP)
            u.skeys[pos] = ((unsigned long long)(~__float_as_uint(p)) << 32) | (unsigned)(4*i + c);
        }
      }
    }
  } else {
    const unsigned thr = thr_sh;
    for (unsigned j = tid; j < tot; j += 1024){
      unsigned long long k = sp64[j];
      uint32_t lb = (uint32_t)(k >> 32);
      if ((fkey(lb) >> 20) >= thr){
        unsigned pos = atomicAdd(&n_sh, 1u);
        float p = expf(__uint_as_float(lb) - 16.0f) / S16;
        if (pos < CAP)
          u.skeys[pos] = ((unsigned long long)(~__float_as_uint(p)) << 32) | (k & 0xFFFFFFFFull);
      }
    }
  }
  __syncthreads();
  unsigned n = n_sh; if (n > CAP) n = CAP;   // scan guarantees <= CAP

  // pad + bitonic sort (ascending == p desc, stable via embedded idx)
  unsigned N2 = 2; while (N2 < n) N2 <<= 1;
  for (unsigned i = n + tid; i < N2; i += 1024) u.skeys[i] = 0xFFFFFFFFFFFFFFFFull;
  __syncthreads();
  for (unsigned k = 2; k <= N2; k <<= 1){
    for (unsigned j = k >> 1; j > 0; j >>= 1){
      for (unsigned i = tid; i < N2; i += 1024){
        unsigned ixj = i ^ j;
        if (ixj > i){
          unsigned long long a = u.skeys[i], c2 = u.skeys[ixj];
          bool up = ((i & k) == 0u);
          if ((a > c2) == up){ u.skeys[i] = c2; u.skeys[ixj] = a; }
        }
      }
      __syncthreads();
    }
  }

  // 0.9 cumsum crossing (chunked partials in red[], thread-0 walk)
  unsigned C = (n + 1023) >> 10;
  {
    unsigned lo = tid * C; if (lo > n) lo = n;
    unsigned hi = lo + C;  if (hi > n) hi = n;
    float s = 0.f;
    for (unsigned j = lo; j < hi; ++j) s += pdecode(u.skeys[j]);
    red[tid] = s;
  }
  __syncthreads();
  if (tid == 0){
    float run = 0.f; int cut = (int)n - 1; int t = 0;
    for (; t < 1024; ++t){ float cs = red[t]; if (run + cs >= 0.9f) break; run += cs; }
    if (t < 1024){
      float c2 = run;
      for (unsigned j = (unsigned)t * C; j < n; ++j){
        c2 += pdecode(u.skeys[j]);
        if (c2 >= 0.9f){ cut = (int)j; break; }
      }
    }
    cut_sh = cut;
  }
  __syncthreads();
  const int cut = cut_sh;

  // gumbel argmax over sorted positions 0..cut
  float best = -INFINITY; unsigned bj = 0x7FFFFFFFu;
  for (int j = tid; j <= cut; j += 1024){
    float p = pdecode(u.skeys[j]);
    float sc = logf(p) + gumbel_at((uint32_t)b * (uint32_t)VOCAB + (uint32_t)j);
    if (sc > best || (sc == best && (unsigned)j < bj)){ best = sc; bj = (unsigned)j; }
  }
  for (int off = 32; off > 0; off >>= 1){
    float osc = __shfl_down(best, off, 64);
    unsigned oj = __shfl_down(bj, off, 64);
    if (osc > best || (osc == best && oj < bj)){ best = osc; bj = oj; }
  }
  if ((tid & 63) == 0){
    uint32_t ub = __float_as_uint(best);
    uint32_t ou = (ub >> 31) ? ~ub : (ub | 0x80000000u);
    wavewin[tid >> 6] = ((unsigned long long)ou << 32) |
                        (unsigned long long)(0xFFFFFFFFu - bj);   // tie -> min j
  }
  __syncthreads();
  if (tid == 0){
    unsigned long long bb = 0ull;
    for (int w = 0; w < 16; ++w){ unsigned long long x = wavewin[w]; if (x > bb) bb = x; }
    unsigned jwin = 0xFFFFFFFFu - (unsigned)(bb & 0xFFFFFFFFull);
    // k_stream's 1e-5 fill is ordered before this dispatch (same stream).
    orow[(size_t)(u.skeys[jwin] & 0xFFFFFFFFull)] = 1e5f;
  }
}

extern "C" void kernel_launch(void* const* d_in, const int* in_sizes, int n_in,
                              void* d_out, int out_size, void* d_ws, size_t ws_size,
                              hipStream_t stream) {
  // d_in[0]=input_ids (unused), d_in[1]=scores [256*128000] f32, d_in[2]=green [128000] f32
  const float* scores = (const float*)d_in[1];
  const float* green  = (const float*)d_in[2];
  float* out = (float*)d_out;

  // ws layout: spill[256*32*256] u64 (16 MB) | counts[8192] u32 | pmax[8192] f32 | psum[8192] f32
  unsigned long long* spill = (unsigned long long*)d_ws;
  unsigned* counts = (unsigned*)(spill + (size_t)BATCH * NSEG * WSEG);
  float* pmax = (float*)(counts + BATCH * NSEG);
  float* psum = pmax + BATCH * NSEG;
  (void)ws_size;

  hipLaunchKernelGGL(k_stream, dim3(BATCH*8), dim3(256),  0, stream,
                     scores, green, out, spill, counts, pmax, psum);
  hipLaunchKernelGGL(k_row,    dim3(BATCH),   dim3(1024), 0, stream,
                     scores, green, out, spill, counts, pmax, psum);
}

// Round 6
// 332.380 us; speedup vs baseline: 2.5634x; 1.0300x over previous
//
#include <hip/hip_runtime.h>
#include <cstdint>
#include <cstddef>

#define BATCH 256
#define VOCAB 128000
#define V4 (VOCAB/4)
#define NBINS 4096
#define CAP 4096            // power of 2: bitonic padding can never overflow
#define WSEG 256            // per-wave spill capacity (u64): E~179 hits, +5.9 sigma
#define NSEG 32             // waves per row (8 blocks x 4 waves)
#define SPILLCAP 6144       // per-row compacted cap (48KB LDS): E~5734, +5.5 sigma
#define GATE_SPILL 8.0f
#define SPILL_BIN 3088u     // fkey(bits(8.0f)) >> 20 (8.0 is a bin boundary)
#define GATE_HIST 1.0f
#define M44 0xFFFFFFFFFFFull
#define FIX 16777216.0f     // 2^24 fixed-point mass scale (deterministic hist)
#define FIXINV 5.9604644775390625e-8f

__device__ __forceinline__ uint32_t rotl32(uint32_t v, int r){ return (v<<r)|(v>>(32-r)); }

// threefry2x32 with key (0,1) — jax.random.key(1) -> key data [0,1]
__device__ __forceinline__ void threefry2x32_01(uint32_t& x0, uint32_t& x1){
  const uint32_t ks0=0u, ks1=1u, ks2=0x1BD11BDAu ^ 0u ^ 1u;
  x0+=ks0; x1+=ks1;
#define TF_R(r) { x0+=x1; x1=rotl32(x1,(r)); x1^=x0; }
  TF_R(13) TF_R(15) TF_R(26) TF_R(6)
  x0+=ks1; x1+=ks2+1u;
  TF_R(17) TF_R(29) TF_R(16) TF_R(24)
  x0+=ks2; x1+=ks0+2u;
  TF_R(13) TF_R(15) TF_R(26) TF_R(6)
  x0+=ks0; x1+=ks1+3u;
  TF_R(17) TF_R(29) TF_R(16) TF_R(24)
  x0+=ks1; x1+=ks2+4u;
  TF_R(13) TF_R(15) TF_R(26) TF_R(6)
  x0+=ks2; x1+=ks0+5u;
#undef TF_R
}

// JAX partitionable threefry draw: counter=(0,z), bits = x0 ^ x1. Verified (absmax 0).
__device__ __forceinline__ float gumbel_at(uint32_t z){
  uint32_t x0 = 0u, x1 = z;
  threefry2x32_01(x0, x1);
  uint32_t bits = x0 ^ x1;
  uint32_t fb = (bits >> 9) | 0x3F800000u;
  float f = __uint_as_float(fb) - 1.0f;
  const float tiny = 1.17549435e-38f;
  float uu = fmaxf(tiny, f + tiny);
  return -logf(-logf(uu));
}

__device__ __forceinline__ uint32_t fkey(uint32_t u){
  return (u >> 31) ? ~u : (u | 0x80000000u);
}
__device__ __forceinline__ float pdecode(unsigned long long k){
  return __uint_as_float(~(uint32_t)(k >> 32));
}

// ---------- kernel 1: pure streaming, 8 blocks/row x 256 threads ----------
// Per wave: private spill segment, REGISTER counter (no atomics anywhere),
// ballot-compacted (l_bits,idx) spill of l >= 8. No LDS. Register double-buffer:
// group g+1's 8 float4 loads are issued BEFORE group g is processed, so HBM
// latency hides under the VALU chain. Per-thread visit order identical to R5
// (bit-identical m / S16 / spill contents).
__global__ __launch_bounds__(256, 4) void k_stream(
    const float* __restrict__ scores, const float* __restrict__ green,
    float* __restrict__ out, unsigned long long* __restrict__ spill,
    unsigned* __restrict__ counts, float* __restrict__ pmax,
    float* __restrict__ psum)
{
  const int blk = blockIdx.x;
  const int b = blk >> 3, q = blk & 7;
  const int tid = threadIdx.x, lane = tid & 63, wv = tid >> 6;
  const int base = q * 4000;                       // float4 base (V4/8 = 4000)
  const float4* row4 = (const float4*)(scores + (size_t)b * VOCAB);
  const float4* grn4 = (const float4*)green;
  float4* o4 = (float4*)(out + (size_t)b * VOCAB);
  const int sidx = (q << 2) | wv;
  unsigned long long* seg = spill + ((size_t)b * NSEG + sidx) * WSEG;
  const float4 fv = make_float4(1e-5f, 1e-5f, 1e-5f, 1e-5f);

  float lm = -INFINITY, ls16 = 0.f;
  unsigned wcnt = 0u;                              // wave-uniform, in-register

#define SP1(LV, IDX) do { \
    float l_ = (LV); \
    lm = fmaxf(lm, l_); \
    ls16 += expf(l_ - 16.0f); \
    bool pr_ = (l_ >= GATE_SPILL); \
    unsigned long long mk_ = __ballot(pr_); \
    if (pr_){ \
      unsigned pos_ = wcnt + (unsigned)__popcll(mk_ & ((1ull << lane) - 1ull)); \
      if (pos_ < WSEG) \
        seg[pos_] = ((unsigned long long)__float_as_uint(l_) << 32) | (IDX); \
    } \
    wcnt += (unsigned)__popcll(mk_); \
  } while(0)

#define SP4(SV, GV, II) do { \
    SP1(fmaf(2.f, (GV).x, (SV).x), (unsigned)(4*(II)+0)); \
    SP1(fmaf(2.f, (GV).y, (SV).y), (unsigned)(4*(II)+1)); \
    SP1(fmaf(2.f, (GV).z, (SV).z), (unsigned)(4*(II)+2)); \
    SP1(fmaf(2.f, (GV).w, (SV).w), (unsigned)(4*(II)+3)); \
  } while(0)

  // 4000 float4s per block = 3 quad-strides (3072) + 3 singles (768) + 160-tail.
  // Prefetch group 0, then per group: issue next group's loads, process current.
  float4 sa, sb, sc, sd, ga, gb, gc, gd;
  {
    const int i0 = base + tid;
    sa = row4[i0]; sb = row4[i0+256]; sc = row4[i0+512]; sd = row4[i0+768];
    ga = grn4[i0]; gb = grn4[i0+256]; gc = grn4[i0+512]; gd = grn4[i0+768];
  }
  #pragma unroll
  for (int g = 0; g < 3; ++g){
    const int cur = base + tid + g*1024;
    const int nxt = cur + 1024;
    float4 ta, tb, tc, td, ua, ub, uc, ud;
    if (g < 2){                                    // next is a quad group
      ta = row4[nxt]; tb = row4[nxt+256]; tc = row4[nxt+512]; td = row4[nxt+768];
      ua = grn4[nxt]; ub = grn4[nxt+256]; uc = grn4[nxt+512]; ud = grn4[nxt+768];
    } else {                                       // next is the 3-single group
      ta = row4[nxt]; tb = row4[nxt+256]; tc = row4[nxt+512];
      ua = grn4[nxt]; ub = grn4[nxt+256]; uc = grn4[nxt+512];
      td = tc; ud = uc;                            // unused
    }
    o4[cur] = fv; o4[cur+256] = fv; o4[cur+512] = fv; o4[cur+768] = fv;
    SP4(sa, ga, cur); SP4(sb, gb, cur+256); SP4(sc, gc, cur+512); SP4(sd, gd, cur+768);
    sa = ta; sb = tb; sc = tc; sd = td; ga = ua; gb = ub; gc = uc; gd = ud;
  }
  {
    const int i0 = base + 3072 + tid;
    o4[i0] = fv; o4[i0+256] = fv; o4[i0+512] = fv;
    SP4(sa, ga, i0); SP4(sb, gb, i0+256); SP4(sc, gc, i0+512);
  }
  if (tid < 160){
    // waves 0,1 full; wave 2 half-active (ballot covers active lanes only;
    // lane 0 of wave 2 is active so its final wcnt is correct); wave 3 idle.
    const int i0 = base + 3840 + tid;
    float4 s = row4[i0];
    float4 g = grn4[i0];
    o4[i0] = fv;
    SP4(s, g, i0);
  }
#undef SP4
#undef SP1

  // per-wave reductions (fixed shfl butterfly -> deterministic), lane0 writes
  for (int off = 32; off > 0; off >>= 1){
    lm = fmaxf(lm, __shfl_down(lm, off, 64));
    ls16 += __shfl_down(ls16, off, 64);
  }
  if (lane == 0){
    const int gi = b * NSEG + sidx;
    pmax[gi] = lm; psum[gi] = ls16; counts[gi] = wcnt;
  }
}

// ---------- kernel 2: per-row select + sort + sample (256 blocks x 1024) ----------
__global__ __launch_bounds__(1024) void k_row(
    const float* __restrict__ scores, const float* __restrict__ green,
    float* __restrict__ out, const unsigned long long* __restrict__ spill,
    const unsigned* __restrict__ counts, const float* __restrict__ pmax,
    const float* __restrict__ psum)
{
  __shared__ unsigned long long sp64[SPILLCAP];          // 48 KB (l_bits<<32)|idx
  __shared__ union {
    unsigned long long hist[NBINS];                      // 32 KB packed count|mass
    unsigned long long skeys[CAP];                       // 32 KB sort keys
  } u;
  __shared__ float red[1024];
  __shared__ unsigned long long wavewin[16];
  __shared__ unsigned segoff[NSEG + 1];
  __shared__ float m_sh, s16_sh;
  __shared__ unsigned n_sh, thr_sh, fb_sh;
  __shared__ int cut_sh;

  const int b = blockIdx.x, tid = threadIdx.x;
  const float* srow = scores + (size_t)b * VOCAB;
  float* orow = out + (size_t)b * VOCAB;

  for (int i = tid; i < NBINS; i += 1024) u.hist[i] = 0ull;
  if (tid == 0){
    unsigned tot = 0u, fb = 0u;
    float mm = -INFINITY, ss = 0.f;
    for (int s = 0; s < NSEG; ++s){
      unsigned c = counts[b*NSEG + s];
      segoff[s] = tot;
      if (c > WSEG) fb = 1u;                 // wave segment overflowed (never expected)
      tot += c;
      mm = fmaxf(mm, pmax[b*NSEG + s]);      // max: order-free, exact
      ss += psum[b*NSEG + s];                // fixed order: deterministic
    }
    segoff[NSEG] = tot;
    if (tot > SPILLCAP) fb = 1u;
    m_sh = mm; s16_sh = ss; fb_sh = fb; n_sh = 0u;
  }
  __syncthreads();
  const float m = m_sh, S16 = s16_sh;
  const unsigned tot = segoff[NSEG];
  unsigned fb = fb_sh;

  if (!fb){
    // coalesced gather of 32 segments into compacted sp64
    for (int s = 0; s < NSEG; ++s){
      const unsigned c0 = segoff[s], cl = segoff[s+1] - c0;
      const unsigned long long* seg = spill + ((size_t)b*NSEG + s)*WSEG;
      for (unsigned j = tid; j < cl; j += 1024) sp64[c0 + j] = seg[j];
    }
    __syncthreads();
    // candidate-only hist (~6 atomics/thread)
    for (unsigned j = tid; j < tot; j += 1024){
      uint32_t lb = (uint32_t)(sp64[j] >> 32);
      atomicAdd(&u.hist[fkey(lb) >> 20],
                (1ull<<44) | (unsigned long long)(expf(__uint_as_float(lb) - 16.0f) * FIX));
    }
    __syncthreads();
    // threshold scan vs TRUE total S16. NO safety bin: hist is complete for all
    // bins >= SPILL_BIN (every l>=8 item histogrammed; fixed-point error ~2e-6
    // rel), so the 0.903-vs-0.9 margin alone guarantees the set contains the
    // 0.9-crossing prefix. Dropping it shrinks n (and the bitonic sort) ~2-4x.
    if (tid == 0){
      float target = 0.903f * S16;
      int top = (int)(fkey(__float_as_uint(m)) >> 20);   // bins above bin(m) empty
      float acc = 0.f; unsigned c = 0; unsigned result = (unsigned)top;
      for (int bin = top; bin >= 0; --bin){
        unsigned long long h = u.hist[bin];
        unsigned cb = (unsigned)(h >> 44);
        if (c + cb > CAP) break;
        acc += (float)(h & M44) * FIXINV; c += cb; result = (unsigned)bin;
        if (acc >= target) break;
      }
      thr_sh = result;
      if (result < SPILL_BIN) fb_sh = 1u;   // spill-hist incomplete below l=8
    }
    __syncthreads();
    fb = fb_sh;
  }

  if (fb){
    // full-row fallback (never taken on this input): complete hist, rescan, extract
    for (int i = tid; i < NBINS; i += 1024) u.hist[i] = 0ull;
    __syncthreads();
    const float4* row4 = (const float4*)srow;
    const float4* grn4 = (const float4*)green;
    for (int i = tid; i < V4; i += 1024){
      float4 s = row4[i], g = grn4[i];
      #pragma unroll
      for (int c = 0; c < 4; ++c){
        float l = fmaf(2.f, (&g.x)[c], (&s.x)[c]);
        if (l >= GATE_HIST)
          atomicAdd(&u.hist[fkey(__float_as_uint(l)) >> 20],
                    (1ull<<44) | (unsigned long long)(expf(l - 16.0f) * FIX));
      }
    }
    __syncthreads();
    if (tid == 0){
      float target = 0.903f * S16;
      int top = (int)(fkey(__float_as_uint(m)) >> 20);
      float acc = 0.f; unsigned c = 0; unsigned result = (unsigned)top;
      for (int bin = top; bin >= 0; --bin){
        unsigned long long h = u.hist[bin];
        unsigned cb = (unsigned)(h >> 44);
        if (c + cb > CAP) break;
        acc += (float)(h & M44) * FIXINV; c += cb; result = (unsigned)bin;
        if (acc >= target) break;
      }
      thr_sh = result;
    }
    __syncthreads();
    const unsigned thr = thr_sh;
    for (int i = tid; i < V4; i += 1024){
      float4 s = row4[i], g = grn4[i];
      #pragma unroll
      for (int c = 0; c < 4; ++c){
        float l = fmaf(2.f, (&g.x)[c], (&s.x)[c]);
        if ((fkey(__float_as_uint(l)) >> 20) >= thr){
          unsigned pos = atomicAdd(&n_sh, 1u);
          float p = expf(l - 16.0f) / S16;
          if (pos < CAP)
            u.skeys[pos] = ((unsigned long long)(~__float_as_uint(p)) << 32) | (unsigned)(4*i + c);
        }
      }
    }
  } else {
    const unsigned thr = thr_sh;
    for (unsigned j = tid; j < tot; j += 1024){
      unsigned long long k = sp64[j];
      uint32_t lb = (uint32_t)(k >> 32);
      if ((fkey(lb) >> 20) >= thr){
        unsigned pos = atomicAdd(&n_sh, 1u);
        float p = expf(__uint_as_float(lb) - 16.0f) / S16;
        if (pos < CAP)
          u.skeys[pos] = ((unsigned long long)(~__float_as_uint(p)) << 32) | (k & 0xFFFFFFFFull);
      }
    }
  }
  __syncthreads();
  unsigned n = n_sh; if (n > CAP) n = CAP;   // scan guarantees <= CAP

  // pad + bitonic sort (ascending == p desc, stable via embedded idx)
  unsigned N2 = 2; while (N2 < n) N2 <<= 1;
  for (unsigned i = n + tid; i < N2; i += 1024) u.skeys[i] = 0xFFFFFFFFFFFFFFFFull;
  __syncthreads();
  for (unsigned k = 2; k <= N2; k <<= 1){
    for (unsigned j = k >> 1; j > 0; j >>= 1){
      for (unsigned i = tid; i < N2; i += 1024){
        unsigned ixj = i ^ j;
        if (ixj > i){
          unsigned long long a = u.skeys[i], c2 = u.skeys[ixj];
          bool up = ((i & k) == 0u);
          if ((a > c2) == up){ u.skeys[i] = c2; u.skeys[ixj] = a; }
        }
      }
      __syncthreads();
    }
  }

  // 0.9 cumsum crossing (chunked partials in red[], thread-0 walk)
  unsigned C = (n + 1023) >> 10;
  {
    unsigned lo = tid * C; if (lo > n) lo = n;
    unsigned hi = lo + C;  if (hi > n) hi = n;
    float s = 0.f;
    for (unsigned j = lo; j < hi; ++j) s += pdecode(u.skeys[j]);
    red[tid] = s;
  }
  __syncthreads();
  if (tid == 0){
    float run = 0.f; int cut = (int)n - 1; int t = 0;
    for (; t < 1024; ++t){ float cs = red[t]; if (run + cs >= 0.9f) break; run += cs; }
    if (t < 1024){
      float c2 = run;
      for (unsigned j = (unsigned)t * C; j < n; ++j){
        c2 += pdecode(u.skeys[j]);
        if (c2 >= 0.9f){ cut = (int)j; break; }
      }
    }
    cut_sh = cut;
  }
  __syncthreads();
  const int cut = cut_sh;

  // gumbel argmax over sorted positions 0..cut
  float best = -INFINITY; unsigned bj = 0x7FFFFFFFu;
  for (int j = tid; j <= cut; j += 1024){
    float p = pdecode(u.skeys[j]);
    float sc = logf(p) + gumbel_at((uint32_t)b * (uint32_t)VOCAB + (uint32_t)j);
    if (sc > best || (sc == best && (unsigned)j < bj)){ best = sc; bj = (unsigned)j; }
  }
  for (int off = 32; off > 0; off >>= 1){
    float osc = __shfl_down(best, off, 64);
    unsigned oj = __shfl_down(bj, off, 64);
    if (osc > best || (osc == best && oj < bj)){ best = osc; bj = oj; }
  }
  if ((tid & 63) == 0){
    uint32_t ub = __float_as_uint(best);
    uint32_t ou = (ub >> 31) ? ~ub : (ub | 0x80000000u);
    wavewin[tid >> 6] = ((unsigned long long)ou << 32) |
                        (unsigned long long)(0xFFFFFFFFu - bj);   // tie -> min j
  }
  __syncthreads();
  if (tid == 0){
    unsigned long long bb = 0ull;
    for (int w = 0; w < 16; ++w){ unsigned long long x = wavewin[w]; if (x > bb) bb = x; }
    unsigned jwin = 0xFFFFFFFFu - (unsigned)(bb & 0xFFFFFFFFull);
    // k_stream's 1e-5 fill is ordered before this dispatch (same stream).
    orow[(size_t)(u.skeys[jwin] & 0xFFFFFFFFull)] = 1e5f;
  }
}

extern "C" void kernel_launch(void* const* d_in, const int* in_sizes, int n_in,
                              void* d_out, int out_size, void* d_ws, size_t ws_size,
                              hipStream_t stream) {
  // d_in[0]=input_ids (unused), d_in[1]=scores [256*128000] f32, d_in[2]=green [128000] f32
  const float* scores = (const float*)d_in[1];
  const float* green  = (const float*)d_in[2];
  float* out = (float*)d_out;

  // ws layout: spill[256*32*256] u64 (16 MB) | counts[8192] u32 | pmax[8192] f32 | psum[8192] f32
  unsigned long long* spill = (unsigned long long*)d_ws;
  unsigned* counts = (unsigned*)(spill + (size_t)BATCH * NSEG * WSEG);
  float* pmax = (float*)(counts + BATCH * NSEG);
  float* psum = pmax + BATCH * NSEG;
  (void)ws_size;

  hipLaunchKernelGGL(k_stream, dim3(BATCH*8), dim3(256),  0, stream,
                     scores, green, out, spill, counts, pmax, psum);
  hipLaunchKernelGGL(k_row,    dim3(BATCH),   dim3(1024), 0, stream,
                     scores, green, out, spill, counts, pmax, psum);
}

// Round 8
// 302.072 us; speedup vs baseline: 2.8207x; 1.1003x over previous
//
#include <hip/hip_runtime.h>
#include <cstdint>
#include <cstddef>

#define BATCH 256
#define VOCAB 128000
#define V4 (VOCAB/4)
#define NBINS 4096
#define CAP 4096            // power of 2: bitonic padding can never overflow
#define WSEG 256            // per-wave spill capacity (u64): E~179 hits, +5.9 sigma
#define NSEG 32             // waves per row (8 blocks x 4 waves)
#define SPILLCAP 6144       // per-row compacted cap (48KB LDS): E~5734, +5.5 sigma
#define GATE_SPILL 8.0f
#define SPILL_BIN 3088u     // fkey(bits(8.0f)) >> 20 (8.0 is a bin boundary)
#define GATE_HIST 1.0f
#define M44 0xFFFFFFFFFFFull
#define FIX 16777216.0f     // 2^24 fixed-point mass scale (deterministic hist)
#define FIXINV 5.9604644775390625e-8f

__device__ __forceinline__ uint32_t rotl32(uint32_t v, int r){ return (v<<r)|(v>>(32-r)); }

// threefry2x32 with key (0,1) — jax.random.key(1) -> key data [0,1]
__device__ __forceinline__ void threefry2x32_01(uint32_t& x0, uint32_t& x1){
  const uint32_t ks0=0u, ks1=1u, ks2=0x1BD11BDAu ^ 0u ^ 1u;
  x0+=ks0; x1+=ks1;
#define TF_R(r) { x0+=x1; x1=rotl32(x1,(r)); x1^=x0; }
  TF_R(13) TF_R(15) TF_R(26) TF_R(6)
  x0+=ks1; x1+=ks2+1u;
  TF_R(17) TF_R(29) TF_R(16) TF_R(24)
  x0+=ks2; x1+=ks0+2u;
  TF_R(13) TF_R(15) TF_R(26) TF_R(6)
  x0+=ks0; x1+=ks1+3u;
  TF_R(17) TF_R(29) TF_R(16) TF_R(24)
  x0+=ks1; x1+=ks2+4u;
  TF_R(13) TF_R(15) TF_R(26) TF_R(6)
  x0+=ks2; x1+=ks0+5u;
#undef TF_R
}

// JAX partitionable threefry draw: counter=(0,z), bits = x0 ^ x1. Verified (absmax 0).
__device__ __forceinline__ float gumbel_at(uint32_t z){
  uint32_t x0 = 0u, x1 = z;
  threefry2x32_01(x0, x1);
  uint32_t bits = x0 ^ x1;
  uint32_t fb = (bits >> 9) | 0x3F800000u;
  float f = __uint_as_float(fb) - 1.0f;
  const float tiny = 1.17549435e-38f;
  float uu = fmaxf(tiny, f + tiny);
  return -logf(-logf(uu));
}

__device__ __forceinline__ uint32_t fkey(uint32_t u){
  return (u >> 31) ? ~u : (u | 0x80000000u);
}
__device__ __forceinline__ float pdecode(unsigned long long k){
  return __uint_as_float(~(uint32_t)(k >> 32));
}

// native clang vector for nontemporal builtin (HIP_vector_type is a struct)
typedef float vfloat4 __attribute__((ext_vector_type(4)));
__device__ __forceinline__ void ntstore4(float4* p, float4 v){
  vfloat4 nv; nv.x = v.x; nv.y = v.y; nv.z = v.z; nv.w = v.w;
  __builtin_nontemporal_store(nv, (vfloat4*)p);
}

// ---------- kernel 1: pure streaming, 8 blocks/row x 256 threads ----------
// Per wave: private spill segment, REGISTER counter (no atomics anywhere),
// ballot-compacted (l_bits,idx) spill of l >= 8. No LDS. Out-fill uses
// non-temporal stores (out is write-once; keep L2 for scores/green/spill).
__global__ __launch_bounds__(256, 4) void k_stream(
    const float* __restrict__ scores, const float* __restrict__ green,
    float* __restrict__ out, unsigned long long* __restrict__ spill,
    unsigned* __restrict__ counts, float* __restrict__ pmax,
    float* __restrict__ psum)
{
  const int blk = blockIdx.x;
  const int b = blk >> 3, q = blk & 7;
  const int tid = threadIdx.x, lane = tid & 63, wv = tid >> 6;
  const int base = q * 4000;                       // float4 base (V4/8 = 4000)
  const float4* row4 = (const float4*)(scores + (size_t)b * VOCAB);
  const float4* grn4 = (const float4*)green;
  float4* o4 = (float4*)(out + (size_t)b * VOCAB);
  const int sidx = (q << 2) | wv;
  unsigned long long* seg = spill + ((size_t)b * NSEG + sidx) * WSEG;
  const float4 fv = make_float4(1e-5f, 1e-5f, 1e-5f, 1e-5f);

  float lm = -INFINITY, ls16 = 0.f;
  unsigned wcnt = 0u;                              // wave-uniform, in-register

#define SP1(LV, IDX) do { \
    float l_ = (LV); \
    lm = fmaxf(lm, l_); \
    ls16 += expf(l_ - 16.0f); \
    bool pr_ = (l_ >= GATE_SPILL); \
    unsigned long long mk_ = __ballot(pr_); \
    if (pr_){ \
      unsigned pos_ = wcnt + (unsigned)__popcll(mk_ & ((1ull << lane) - 1ull)); \
      if (pos_ < WSEG) \
        seg[pos_] = ((unsigned long long)__float_as_uint(l_) << 32) | (IDX); \
    } \
    wcnt += (unsigned)__popcll(mk_); \
  } while(0)

#define SP4(SV, GV, II) do { \
    SP1(fmaf(2.f, (GV).x, (SV).x), (unsigned)(4*(II)+0)); \
    SP1(fmaf(2.f, (GV).y, (SV).y), (unsigned)(4*(II)+1)); \
    SP1(fmaf(2.f, (GV).z, (SV).z), (unsigned)(4*(II)+2)); \
    SP1(fmaf(2.f, (GV).w, (SV).w), (unsigned)(4*(II)+3)); \
  } while(0)

  // 4000 float4s per block = 3 quad-strides (3072) + 3 singles (768) + 160-tail.
  // Prefetch group 0, then per group: issue next group's loads, process current.
  float4 sa, sb, sc, sd, ga, gb, gc, gd;
  {
    const int i0 = base + tid;
    sa = row4[i0]; sb = row4[i0+256]; sc = row4[i0+512]; sd = row4[i0+768];
    ga = grn4[i0]; gb = grn4[i0+256]; gc = grn4[i0+512]; gd = grn4[i0+768];
  }
  #pragma unroll
  for (int g = 0; g < 3; ++g){
    const int cur = base + tid + g*1024;
    const int nxt = cur + 1024;
    float4 ta, tb, tc, td, ua, ub, uc, ud;
    if (g < 2){                                    // next is a quad group
      ta = row4[nxt]; tb = row4[nxt+256]; tc = row4[nxt+512]; td = row4[nxt+768];
      ua = grn4[nxt]; ub = grn4[nxt+256]; uc = grn4[nxt+512]; ud = grn4[nxt+768];
    } else {                                       // next is the 3-single group
      ta = row4[nxt]; tb = row4[nxt+256]; tc = row4[nxt+512];
      ua = grn4[nxt]; ub = grn4[nxt+256]; uc = grn4[nxt+512];
      td = tc; ud = uc;                            // unused
    }
    ntstore4(&o4[cur], fv); ntstore4(&o4[cur+256], fv);
    ntstore4(&o4[cur+512], fv); ntstore4(&o4[cur+768], fv);
    SP4(sa, ga, cur); SP4(sb, gb, cur+256); SP4(sc, gc, cur+512); SP4(sd, gd, cur+768);
    sa = ta; sb = tb; sc = tc; sd = td; ga = ua; gb = ub; gc = uc; gd = ud;
  }
  {
    const int i0 = base + 3072 + tid;
    ntstore4(&o4[i0], fv); ntstore4(&o4[i0+256], fv); ntstore4(&o4[i0+512], fv);
    SP4(sa, ga, i0); SP4(sb, gb, i0+256); SP4(sc, gc, i0+512);
  }
  if (tid < 160){
    // waves 0,1 full; wave 2 half-active (ballot covers active lanes only;
    // lane 0 of wave 2 is active so its final wcnt is correct); wave 3 idle.
    const int i0 = base + 3840 + tid;
    float4 s = row4[i0];
    float4 g = grn4[i0];
    ntstore4(&o4[i0], fv);
    SP4(s, g, i0);
  }
#undef SP4
#undef SP1

  // per-wave reductions (fixed shfl butterfly -> deterministic), lane0 writes
  for (int off = 32; off > 0; off >>= 1){
    lm = fmaxf(lm, __shfl_down(lm, off, 64));
    ls16 += __shfl_down(ls16, off, 64);
  }
  if (lane == 0){
    const int gi = b * NSEG + sidx;
    pmax[gi] = lm; psum[gi] = ls16; counts[gi] = wcnt;
  }
}

// ---------- kernel 2: per-row select + sort + sample (256 blocks x 1024) ----------
__global__ __launch_bounds__(1024) void k_row(
    const float* __restrict__ scores, const float* __restrict__ green,
    float* __restrict__ out, const unsigned long long* __restrict__ spill,
    const unsigned* __restrict__ counts, const float* __restrict__ pmax,
    const float* __restrict__ psum)
{
  __shared__ unsigned long long sp64[SPILLCAP];          // 48 KB (l_bits<<32)|idx
  __shared__ union {
    unsigned long long hist[NBINS];                      // 32 KB packed count|mass
    unsigned long long skeys[CAP];                       // 32 KB sort keys
  } u;
  __shared__ float red[1024];
  __shared__ unsigned long long wavewin[16];
  __shared__ unsigned segcnt[NSEG], segoff[NSEG + 1];
  __shared__ float pm_sh[NSEG], ps_sh[NSEG];
  __shared__ float m_sh, s16_sh;
  __shared__ unsigned n_sh, thr_sh, fb_sh;
  __shared__ int cut_sh;

  const int b = blockIdx.x, tid = threadIdx.x, lane = tid & 63;
  const float* srow = scores + (size_t)b * VOCAB;
  float* orow = out + (size_t)b * VOCAB;

  // stage 0: parallel meta loads + hist zero
  if (tid < NSEG){
    segcnt[tid] = counts[b*NSEG + tid];
    pm_sh[tid]  = pmax[b*NSEG + tid];
    ps_sh[tid]  = psum[b*NSEG + tid];
  }
  for (int i = tid; i < NBINS; i += 1024) u.hist[i] = 0ull;
  __syncthreads();
  if (tid == 0){
    unsigned tot = 0u, fb = 0u;
    float mm = -INFINITY, ss = 0.f;
    for (int s = 0; s < NSEG; ++s){              // same order as R6 -> same S16 bits
      unsigned c = segcnt[s];
      segoff[s] = tot;
      if (c > WSEG) fb = 1u;
      tot += c;
      mm = fmaxf(mm, pm_sh[s]);
      ss += ps_sh[s];
    }
    segoff[NSEG] = tot;
    if (tot > SPILLCAP) fb = 1u;
    m_sh = mm; s16_sh = ss; fb_sh = fb; n_sh = 0u;
  }
  __syncthreads();
  const float m = m_sh, S16 = s16_sh;
  const unsigned tot = segoff[NSEG];
  unsigned fb = fb_sh;

  if (!fb){
    // flat gather over all slots: 8 independent loads/thread, fully pipelined.
    // sp64[segoff[s]+j] = seg[s][j] -- bit-identical contents to R6's gather.
    const unsigned long long* segbase = spill + (size_t)b * NSEG * WSEG;
    for (int slot = tid; slot < NSEG*WSEG; slot += 1024){
      const int s = slot >> 8, j = slot & (WSEG-1);
      if ((unsigned)j < segcnt[s]) sp64[segoff[s] + j] = segbase[slot];
    }
    __syncthreads();
    // candidate-only hist (~6 atomics/thread)
    for (unsigned j = tid; j < tot; j += 1024){
      uint32_t lb = (uint32_t)(sp64[j] >> 32);
      atomicAdd(&u.hist[fkey(lb) >> 20],
                (1ull<<44) | (unsigned long long)(expf(__uint_as_float(lb) - 16.0f) * FIX));
    }
    __syncthreads();
    // threshold scan vs TRUE total S16 (hist complete for bins >= SPILL_BIN)
    if (tid == 0){
      float target = 0.903f * S16;
      int top = (int)(fkey(__float_as_uint(m)) >> 20);   // bins above bin(m) empty
      float acc = 0.f; unsigned c = 0; unsigned result = (unsigned)top;
      for (int bin = top; bin >= 0; --bin){
        unsigned long long h = u.hist[bin];
        unsigned cb = (unsigned)(h >> 44);
        if (c + cb > CAP) break;
        acc += (float)(h & M44) * FIXINV; c += cb; result = (unsigned)bin;
        if (acc >= target) break;
      }
      thr_sh = result;
      if (result < SPILL_BIN) fb_sh = 1u;   // spill-hist incomplete below l=8
    }
    __syncthreads();
    fb = fb_sh;
  }

  if (fb){
    // full-row fallback (never taken on this input): complete hist, rescan, extract
    for (int i = tid; i < NBINS; i += 1024) u.hist[i] = 0ull;
    __syncthreads();
    const float4* row4 = (const float4*)srow;
    const float4* grn4 = (const float4*)green;
    for (int i = tid; i < V4; i += 1024){
      float4 s = row4[i], g = grn4[i];
      #pragma unroll
      for (int c = 0; c < 4; ++c){
        float l = fmaf(2.f, (&g.x)[c], (&s.x)[c]);
        if (l >= GATE_HIST)
          atomicAdd(&u.hist[fkey(__float_as_uint(l)) >> 20],
                    (1ull<<44) | (unsigned long long)(expf(l - 16.0f) * FIX));
      }
    }
    __syncthreads();
    if (tid == 0){
      float target = 0.903f * S16;
      int top = (int)(fkey(__float_as_uint(m)) >> 20);
      float acc = 0.f; unsigned c = 0; unsigned result = (unsigned)top;
      for (int bin = top; bin >= 0; --bin){
        unsigned long long h = u.hist[bin];
        unsigned cb = (unsigned)(h >> 44);
        if (c + cb > CAP) break;
        acc += (float)(h & M44) * FIXINV; c += cb; result = (unsigned)bin;
        if (acc >= target) break;
      }
      thr_sh = result;
    }
    __syncthreads();
    const unsigned thr = thr_sh;
    for (int i = tid; i < V4; i += 1024){
      float4 s = row4[i], g = grn4[i];
      #pragma unroll
      for (int c = 0; c < 4; ++c){
        float l = fmaf(2.f, (&g.x)[c], (&s.x)[c]);
        if ((fkey(__float_as_uint(l)) >> 20) >= thr){
          unsigned pos = atomicAdd(&n_sh, 1u);
          float p = expf(l - 16.0f) / S16;
          if (pos < CAP)
            u.skeys[pos] = ((unsigned long long)(~__float_as_uint(p)) << 32) | (unsigned)(4*i + c);
        }
      }
    }
  } else {
    // wave-aggregated extraction: 1 LDS atomic per wave per pass (vs n serialized).
    // Insertion order differs from R6 but keys are unique -> sorted output identical.
    const unsigned thr = thr_sh;
    const unsigned iters = (tot + 1023) >> 10;
    for (unsigned it = 0; it < iters; ++it){
      const unsigned j = it*1024 + tid;
      bool pass = false; unsigned long long k = 0ull; uint32_t lb = 0u;
      if (j < tot){
        k = sp64[j]; lb = (uint32_t)(k >> 32);
        pass = (fkey(lb) >> 20) >= thr;
      }
      unsigned long long mk = __ballot(pass);
      unsigned wbase = 0u;
      if (lane == 0) wbase = atomicAdd(&n_sh, (unsigned)__popcll(mk));
      wbase = (unsigned)__shfl((int)wbase, 0, 64);
      if (pass){
        unsigned pos = wbase + (unsigned)__popcll(mk & ((1ull << lane) - 1ull));
        float p = expf(__uint_as_float(lb) - 16.0f) / S16;
        if (pos < CAP)
          u.skeys[pos] = ((unsigned long long)(~__float_as_uint(p)) << 32) | (k & 0xFFFFFFFFull);
      }
    }
  }
  __syncthreads();
  unsigned n = n_sh; if (n > CAP) n = CAP;   // scan guarantees <= CAP

  // pad + bitonic sort (ascending == p desc, stable via embedded idx)
  unsigned N2 = 2; while (N2 < n) N2 <<= 1;
  for (unsigned i = n + tid; i < N2; i += 1024) u.skeys[i] = 0xFFFFFFFFFFFFFFFFull;
  __syncthreads();
  for (unsigned k = 2; k <= N2; k <<= 1){
    for (unsigned j = k >> 1; j > 0; j >>= 1){
      for (unsigned i = tid; i < N2; i += 1024){
        unsigned ixj = i ^ j;
        if (ixj > i){
          unsigned long long a = u.skeys[i], c2 = u.skeys[ixj];
          bool up = ((i & k) == 0u);
          if ((a > c2) == up){ u.skeys[i] = c2; u.skeys[ixj] = a; }
        }
      }
      __syncthreads();
    }
  }

  // 0.9 cumsum crossing: chunk partials -> Hillis-Steele scan (10 steps) ->
  // the unique boundary thread (excl < 0.9 <= incl) walks its <=C-elem chunk.
  // Replaces the serial thread-0 walk (up to ~500 dependent LDS reads).
  const unsigned C = (n + 1023) >> 10;
  {
    unsigned lo = tid * C; if (lo > n) lo = n;
    unsigned hi = lo + C;  if (hi > n) hi = n;
    float s = 0.f;
    for (unsigned j = lo; j < hi; ++j) s += pdecode(u.skeys[j]);
    red[tid] = s;
  }
  if (tid == 0) cut_sh = (int)n - 1;            // fallback (no crossing found)
  __syncthreads();
  for (int off = 1; off < 1024; off <<= 1){
    float v = red[tid];
    float w = (tid >= off) ? red[tid - off] : 0.f;
    __syncthreads();
    red[tid] = v + w;
    __syncthreads();
  }
  {
    float incl = red[tid];
    float excl = (tid == 0) ? 0.f : red[tid - 1];
    if (excl < 0.9f && incl >= 0.9f){           // unique writer (partials >= 0)
      float c2 = excl;
      unsigned lo = tid * C; if (lo > n) lo = n;
      unsigned hi = lo + C;  if (hi > n) hi = n;
      for (unsigned j = lo; j < hi; ++j){
        c2 += pdecode(u.skeys[j]);
        if (c2 >= 0.9f){ cut_sh = (int)j; break; }
      }
    }
  }
  __syncthreads();
  const int cut = cut_sh;

  // gumbel argmax over sorted positions 0..cut
  float best = -INFINITY; unsigned bj = 0x7FFFFFFFu;
  for (int j = tid; j <= cut; j += 1024){
    float p = pdecode(u.skeys[j]);
    float sc = logf(p) + gumbel_at((uint32_t)b * (uint32_t)VOCAB + (uint32_t)j);
    if (sc > best || (sc == best && (unsigned)j < bj)){ best = sc; bj = (unsigned)j; }
  }
  for (int off = 32; off > 0; off >>= 1){
    float osc = __shfl_down(best, off, 64);
    unsigned oj = __shfl_down(bj, off, 64);
    if (osc > best || (osc == best && oj < bj)){ best = osc; bj = oj; }
  }
  if ((tid & 63) == 0){
    uint32_t ub = __float_as_uint(best);
    uint32_t ou = (ub >> 31) ? ~ub : (ub | 0x80000000u);
    wavewin[tid >> 6] = ((unsigned long long)ou << 32) |
                        (unsigned long long)(0xFFFFFFFFu - bj);   // tie -> min j
  }
  __syncthreads();
  if (tid == 0){
    unsigned long long bb = 0ull;
    for (int w = 0; w < 16; ++w){ unsigned long long x = wavewin[w]; if (x > bb) bb = x; }
    unsigned jwin = 0xFFFFFFFFu - (unsigned)(bb & 0xFFFFFFFFull);
    // k_stream's 1e-5 fill is ordered before this dispatch (same stream).
    orow[(size_t)(u.skeys[jwin] & 0xFFFFFFFFull)] = 1e5f;
  }
}

extern "C" void kernel_launch(void* const* d_in, const int* in_sizes, int n_in,
                              void* d_out, int out_size, void* d_ws, size_t ws_size,
                              hipStream_t stream) {
  // d_in[0]=input_ids (unused), d_in[1]=scores [256*128000] f32, d_in[2]=green [128000] f32
  const float* scores = (const float*)d_in[1];
  const float* green  = (const float*)d_in[2];
  float* out = (float*)d_out;

  // ws layout: spill[256*32*256] u64 (16 MB) | counts[8192] u32 | pmax[8192] f32 | psum[8192] f32
  unsigned long long* spill = (unsigned long long*)d_ws;
  unsigned* counts = (unsigned*)(spill + (size_t)BATCH * NSEG * WSEG);
  float* pmax = (float*)(counts + BATCH * NSEG);
  float* psum = pmax + BATCH * NSEG;
  (void)ws_size;

  hipLaunchKernelGGL(k_stream, dim3(BATCH*8), dim3(256),  0, stream,
                     scores, green, out, spill, counts, pmax, psum);
  hipLaunchKernelGGL(k_row,    dim3(BATCH),   dim3(1024), 0, stream,
                     scores, green, out, spill, counts, pmax, psum);
}